// Round 1
// baseline (3584.123 us; speedup 1.0000x reference)
//
#include <hip/hip_runtime.h>
#include <math.h>

#define T_LEN 4096
#define NBINS 2049          // T/2+1
#define B_SZ 64
#define C_IN 12
#define KM 4
#define NROWS (B_SZ * C_IN) // 768
#define FEAT 64

// ---------------------------------------------------------------------------
// Gains: the Gauss-Seidel UVMD iteration is linear in X with real
// frequency-dependent coefficients. Compute g_k(f) so u_k = g_k * X.
// ---------------------------------------------------------------------------
__global__ void gains_kernel(const float* __restrict__ alpha, // (8,4)
                             const float* __restrict__ tau,   // (8)
                             const float* __restrict__ omega, // (4)
                             float* __restrict__ g)           // (4, NBINS)
{
    int f = blockIdx.x * 256 + threadIdx.x;
    if (f >= NBINS) return;
    float freq = 0.5f * (float)f / 2048.0f;
    float a[4] = {0.f, 0.f, 0.f, 0.f};
    float s = 0.f, lamc = 0.f;
    for (int l = 0; l < 8; ++l) {
        for (int k = 0; k < 4; ++k) {
            float r = 1.f - (s - a[k]) + 0.5f * lamc;
            float d = freq - omega[k];
            float denom = 1.f + alpha[l * 4 + k] * d * d;
            float anew = r / denom;
            s += anew - a[k];
            a[k] = anew;
        }
        lamc += tau[l] * (1.f - s);
    }
    for (int k = 0; k < 4; ++k) g[k * NBINS + f] = a[k];
}

// ---------------------------------------------------------------------------
// Forward FFT: one block per row (b,c). Real input (B,T,C) strided load,
// Stockham radix-2 in LDS, store bins 0..2048.
// ---------------------------------------------------------------------------
__global__ __launch_bounds__(512) void fft_fwd(const float* __restrict__ x,
                                               float2* __restrict__ Xs)
{
    int row = blockIdx.x;           // 0..767
    int b = row / C_IN, c = row % C_IN;
    __shared__ float2 bufA[T_LEN];
    __shared__ float2 bufB[T_LEN];
    for (int t = threadIdx.x; t < T_LEN; t += 512)
        bufA[t] = make_float2(x[(b * T_LEN + t) * C_IN + c], 0.f);
    __syncthreads();
    float2* src = bufA;
    float2* dst = bufB;
    for (int s = 0; s < 12; ++s) {
        int m = 1 << s;
        int l = 2048 >> s;
        for (int p = threadIdx.x; p < 2048; p += 512) {
            int j = p >> s;
            int jm = j << s;
            float2 c0 = src[p];
            float2 c1 = src[p + 2048];
            float ang = -(float)M_PI * (float)j / (float)l;
            float sn, cs;
            sincosf(ang, &sn, &cs);
            float2 d0 = make_float2(c0.x + c1.x, c0.y + c1.y);
            float2 t1 = make_float2(c0.x - c1.x, c0.y - c1.y);
            float2 d1 = make_float2(cs * t1.x - sn * t1.y, cs * t1.y + sn * t1.x);
            dst[jm + p] = d0;
            dst[jm + p + m] = d1;
        }
        __syncthreads();
        float2* tmp = src; src = dst; dst = tmp;
    }
    // 12 swaps -> result back in bufA (== src)
    for (int f = threadIdx.x; f < NBINS; f += 512)
        Xs[(size_t)row * NBINS + f] = src[f];
}

// ---------------------------------------------------------------------------
// Inverse FFT for mode k: S(f) = g_k(|f|) * X(f) (Hermitian), inverse
// Stockham, write real part scaled by 1/T. Output layout (B, C, T).
// ---------------------------------------------------------------------------
__global__ __launch_bounds__(512) void fft_inv(const float2* __restrict__ Xs,
                                               const float* __restrict__ g,
                                               float* __restrict__ mode,
                                               int k)
{
    int row = blockIdx.x;
    __shared__ float2 bufA[T_LEN];
    __shared__ float2 bufB[T_LEN];
    const float* gk = g + k * NBINS;
    for (int f = threadIdx.x; f < T_LEN; f += 512) {
        int fe = (f <= 2048) ? f : (T_LEN - f);
        float2 X = Xs[(size_t)row * NBINS + fe];
        float gv = gk[fe];
        float2 v = make_float2(gv * X.x, gv * X.y);
        if (f > 2048) v.y = -v.y;   // conjugate mirror
        bufA[f] = v;
    }
    __syncthreads();
    float2* src = bufA;
    float2* dst = bufB;
    for (int s = 0; s < 12; ++s) {
        int m = 1 << s;
        int l = 2048 >> s;
        for (int p = threadIdx.x; p < 2048; p += 512) {
            int j = p >> s;
            int jm = j << s;
            float2 c0 = src[p];
            float2 c1 = src[p + 2048];
            float ang = (float)M_PI * (float)j / (float)l;   // +i twiddle
            float sn, cs;
            sincosf(ang, &sn, &cs);
            float2 d0 = make_float2(c0.x + c1.x, c0.y + c1.y);
            float2 t1 = make_float2(c0.x - c1.x, c0.y - c1.y);
            float2 d1 = make_float2(cs * t1.x - sn * t1.y, cs * t1.y + sn * t1.x);
            dst[jm + p] = d0;
            dst[jm + p + m] = d1;
        }
        __syncthreads();
        float2* tmp = src; src = dst; dst = tmp;
    }
    const float inv_n = 1.f / (float)T_LEN;
    for (int t = threadIdx.x; t < T_LEN; t += 512)
        mode[(size_t)row * T_LEN + t] = src[t].x * inv_n;
}

// ---------------------------------------------------------------------------
// Conv1: (B,12,T) -> (B,32,T), kw=7, same pad, fused BN(eval)+ReLU.
// ---------------------------------------------------------------------------
__global__ __launch_bounds__(256) void conv1_kernel(const float* __restrict__ in,
                                                    const float* __restrict__ W,  // (32,12,7), k-offset applied
                                                    const float* __restrict__ bias,
                                                    const float* __restrict__ gamma,
                                                    const float* __restrict__ beta,
                                                    float* __restrict__ out)
{
    int t = blockIdx.x * 256 + threadIdx.x;
    int o = blockIdx.y;
    int b = blockIdx.z;
    const float* wo = W + o * C_IN * 7;
    float acc = 0.f;
    for (int c = 0; c < C_IN; ++c) {
        const float* row = in + (size_t)(b * C_IN + c) * T_LEN;
#pragma unroll
        for (int d = 0; d < 7; ++d) {
            int tt = t + d - 3;
            float v = (tt >= 0 && tt < T_LEN) ? row[tt] : 0.f;
            acc = fmaf(wo[c * 7 + d], v, acc);
        }
    }
    float scale = gamma[o] / sqrtf(1.f + 1e-5f);
    out[((size_t)b * 32 + o) * T_LEN + t] = fmaxf(0.f, (acc + bias[o]) * scale + beta[o]);
}

// ---------------------------------------------------------------------------
// Conv2: (B,32,T) -> (B,64,T), kw=5.
// ---------------------------------------------------------------------------
__global__ __launch_bounds__(256) void conv2_kernel(const float* __restrict__ in,
                                                    const float* __restrict__ W,  // (64,32,5)
                                                    const float* __restrict__ bias,
                                                    const float* __restrict__ gamma,
                                                    const float* __restrict__ beta,
                                                    float* __restrict__ out)
{
    int t = blockIdx.x * 256 + threadIdx.x;
    int o = blockIdx.y;
    int b = blockIdx.z;
    const float* wo = W + o * 32 * 5;
    float acc = 0.f;
    for (int c = 0; c < 32; ++c) {
        const float* row = in + ((size_t)b * 32 + c) * T_LEN;
#pragma unroll
        for (int d = 0; d < 5; ++d) {
            int tt = t + d - 2;
            float v = (tt >= 0 && tt < T_LEN) ? row[tt] : 0.f;
            acc = fmaf(wo[c * 5 + d], v, acc);
        }
    }
    float scale = gamma[o] / sqrtf(1.f + 1e-5f);
    out[((size_t)b * 64 + o) * T_LEN + t] = fmaxf(0.f, (acc + bias[o]) * scale + beta[o]);
}

// ---------------------------------------------------------------------------
// Conv3 + mean over T: (B,64,T) -> feats(B, K*64) at slot k. kw=3.
// One block per (o,b); 256 threads stride over T; tree-reduce.
// ---------------------------------------------------------------------------
__global__ __launch_bounds__(256) void conv3_mean_kernel(const float* __restrict__ in,
                                                         const float* __restrict__ W, // (64,64,3)
                                                         const float* __restrict__ bias,
                                                         const float* __restrict__ gamma,
                                                         const float* __restrict__ beta,
                                                         float* __restrict__ feats,
                                                         int k)
{
    int o = blockIdx.x;
    int b = blockIdx.y;
    float scale = gamma[o] / sqrtf(1.f + 1e-5f);
    float bo = bias[o], beo = beta[o];
    float acc = 0.f;
    for (int t = threadIdx.x; t < T_LEN; t += 256) {
        float s = 0.f;
        for (int c = 0; c < 64; ++c) {
            const float* row = in + ((size_t)b * 64 + c) * T_LEN;
            const float* w = W + (o * 64 + c) * 3;
            float x0 = (t - 1 >= 0) ? row[t - 1] : 0.f;
            float x1 = row[t];
            float x2 = (t + 1 < T_LEN) ? row[t + 1] : 0.f;
            s = fmaf(w[0], x0, s);
            s = fmaf(w[1], x1, s);
            s = fmaf(w[2], x2, s);
        }
        acc += fmaxf(0.f, (s + bo) * scale + beo);
    }
    __shared__ float red[256];
    red[threadIdx.x] = acc;
    __syncthreads();
    for (int st = 128; st > 0; st >>= 1) {
        if (threadIdx.x < st) red[threadIdx.x] += red[threadIdx.x + st];
        __syncthreads();
    }
    if (threadIdx.x == 0)
        feats[b * (KM * FEAT) + k * FEAT + o] = red[0] * (1.f / (float)T_LEN);
}

// ---------------------------------------------------------------------------
// Classifier: feats(B,256) -> relu(@Wc1.T+bc1) -> @Wc2.T+bc2 -> (B,10)
// ---------------------------------------------------------------------------
__global__ __launch_bounds__(128) void classifier_kernel(const float* __restrict__ feats,
                                                         const float* __restrict__ Wc1, // (128,256)
                                                         const float* __restrict__ bc1,
                                                         const float* __restrict__ Wc2, // (10,128)
                                                         const float* __restrict__ bc2,
                                                         float* __restrict__ out)
{
    int b = blockIdx.x;
    int j = threadIdx.x;
    __shared__ float h[128];
    float acc = bc1[j];
    const float* fb = feats + b * 256;
    for (int i = 0; i < 256; ++i) acc = fmaf(fb[i], Wc1[j * 256 + i], acc);
    h[j] = fmaxf(acc, 0.f);
    __syncthreads();
    if (j < 10) {
        float acc2 = bc2[j];
        for (int i = 0; i < 128; ++i) acc2 = fmaf(h[i], Wc2[j * 128 + i], acc2);
        out[b * 10 + j] = acc2;
    }
}

extern "C" void kernel_launch(void* const* d_in, const int* in_sizes, int n_in,
                              void* d_out, int out_size, void* d_ws, size_t ws_size,
                              hipStream_t stream)
{
    const float* x     = (const float*)d_in[0];
    const float* alpha = (const float*)d_in[1];
    const float* tau   = (const float*)d_in[2];
    const float* omega = (const float*)d_in[3];
    const float* W1    = (const float*)d_in[4];
    const float* b1    = (const float*)d_in[5];
    const float* g1    = (const float*)d_in[6];
    const float* be1   = (const float*)d_in[7];
    const float* W2    = (const float*)d_in[8];
    const float* b2    = (const float*)d_in[9];
    const float* g2    = (const float*)d_in[10];
    const float* be2   = (const float*)d_in[11];
    const float* W3    = (const float*)d_in[12];
    const float* b3    = (const float*)d_in[13];
    const float* g3    = (const float*)d_in[14];
    const float* be3   = (const float*)d_in[15];
    const float* Wc1   = (const float*)d_in[16];
    const float* bc1   = (const float*)d_in[17];
    const float* Wc2   = (const float*)d_in[18];
    const float* bc2   = (const float*)d_in[19];

    float* ws = (float*)d_ws;
    // layout (floats):
    float* g     = ws;                                   // 4*2049 = 8196
    float2* Xs   = (float2*)(ws + 8196);                 // 768*2049 float2
    float* mode  = ws + 8196 + (size_t)NROWS * NBINS * 2; // 768*4096
    float* h1    = mode + (size_t)NROWS * T_LEN;          // 64*32*4096
    float* h2    = h1 + (size_t)B_SZ * 32 * T_LEN;        // 64*64*4096
    float* feats = h2 + (size_t)B_SZ * 64 * T_LEN;        // 64*256

    gains_kernel<<<(NBINS + 255) / 256, 256, 0, stream>>>(alpha, tau, omega, g);
    fft_fwd<<<NROWS, 512, 0, stream>>>(x, Xs);

    for (int k = 0; k < KM; ++k) {
        fft_inv<<<NROWS, 512, 0, stream>>>(Xs, g, mode, k);
        conv1_kernel<<<dim3(T_LEN / 256, 32, B_SZ), 256, 0, stream>>>(
            mode, W1 + k * 32 * C_IN * 7, b1 + k * 32, g1 + k * 32, be1 + k * 32, h1);
        conv2_kernel<<<dim3(T_LEN / 256, 64, B_SZ), 256, 0, stream>>>(
            h1, W2 + k * 64 * 32 * 5, b2 + k * 64, g2 + k * 64, be2 + k * 64, h2);
        conv3_mean_kernel<<<dim3(64, B_SZ), 256, 0, stream>>>(
            h2, W3 + k * 64 * 64 * 3, b3 + k * 64, g3 + k * 64, be3 + k * 64, feats, k);
    }

    classifier_kernel<<<B_SZ, 128, 0, stream>>>(feats, Wc1, bc1, Wc2, bc2, (float*)d_out);
}

// Round 2
// 1170.399 us; speedup vs baseline: 3.0623x; 3.0623x over previous
//
#include <hip/hip_runtime.h>
#include <math.h>

#define T_LEN 4096
#define NBINS 2049          // T/2+1
#define B_SZ 64
#define C_IN 12
#define KM 4
#define FEAT 64

// ---------------------------------------------------------------------------
// Gains: the Gauss-Seidel UVMD iteration is linear in X with real
// frequency-only coefficients: u_k = g_k(f) * X(f).
// ---------------------------------------------------------------------------
__global__ void gains_kernel(const float* __restrict__ alpha, // (8,4)
                             const float* __restrict__ tau,   // (8)
                             const float* __restrict__ omega, // (4)
                             float* __restrict__ g)           // (4, NBINS)
{
    int f = blockIdx.x * 256 + threadIdx.x;
    if (f >= NBINS) return;
    float freq = 0.5f * (float)f / 2048.0f;
    float a[4] = {0.f, 0.f, 0.f, 0.f};
    float s = 0.f, lamc = 0.f;
    for (int l = 0; l < 8; ++l) {
        for (int k = 0; k < 4; ++k) {
            float r = 1.f - (s - a[k]) + 0.5f * lamc;
            float d = freq - omega[k];
            float denom = 1.f + alpha[l * 4 + k] * d * d;
            float anew = r / denom;
            s += anew - a[k];
            a[k] = anew;
        }
        lamc += tau[l] * (1.f - s);
    }
    for (int k = 0; k < 4; ++k) g[k * NBINS + f] = a[k];
}

__global__ void zero_kernel(float* __restrict__ p, int n)
{
    int i = blockIdx.x * 256 + threadIdx.x;
    if (i < n) p[i] = 0.f;
}

// ---------------------------------------------------------------------------
// Shared Stockham radix-2 stage loop (sign=-1 fwd, +1 inv). Caller loads
// bufA and __syncthreads() first. Returns buffer holding the result.
// ---------------------------------------------------------------------------
__device__ inline float2* fft_stages(float2* bufA, float2* bufB, float sign)
{
    float2* src = bufA;
    float2* dst = bufB;
    for (int s = 0; s < 12; ++s) {
        int m = 1 << s;
        int l = 2048 >> s;
        for (int p = threadIdx.x; p < 2048; p += 512) {
            int j = p >> s;
            int jm = j << s;
            float2 c0 = src[p];
            float2 c1 = src[p + 2048];
            float ang = sign * (float)M_PI * (float)j / (float)l;
            float sn, cs;
            sincosf(ang, &sn, &cs);
            float2 d0 = make_float2(c0.x + c1.x, c0.y + c1.y);
            float2 t1 = make_float2(c0.x - c1.x, c0.y - c1.y);
            float2 d1 = make_float2(cs * t1.x - sn * t1.y, cs * t1.y + sn * t1.x);
            dst[jm + p] = d0;
            dst[jm + p + m] = d1;
        }
        __syncthreads();
        float2* tmp = src; src = dst; dst = tmp;
    }
    return src;   // 12 swaps -> back to bufA
}

// ---------------------------------------------------------------------------
// Forward FFT, 2 real rows (channels c0, c0+1) packed into one complex FFT.
// Unpack via Hermitian split; store both spectra rows (bins 0..2048).
// ---------------------------------------------------------------------------
__global__ __launch_bounds__(512) void fft_fwd_packed(const float* __restrict__ x,
                                                      float2* __restrict__ Xs)
{
    int rp = blockIdx.x;            // 0..383
    int b = rp / 6, c0 = (rp % 6) * 2;
    __shared__ float2 bufA[T_LEN];
    __shared__ float2 bufB[T_LEN];
    for (int t = threadIdx.x; t < T_LEN; t += 512) {
        const float* px = x + ((size_t)b * T_LEN + t) * C_IN + c0;
        bufA[t] = make_float2(px[0], px[1]);
    }
    __syncthreads();
    float2* Z = fft_stages(bufA, bufB, -1.f);
    size_t row = (size_t)b * C_IN + c0;
    for (int f = threadIdx.x; f <= 2048; f += 512) {
        float2 z  = Z[f];
        float2 zm = Z[(T_LEN - f) & (T_LEN - 1)];
        // Xa = (Z + conj(Zm))/2 ; Xb = (Z - conj(Zm))/(2i)
        Xs[row * NBINS + f]       = make_float2(0.5f * (z.x + zm.x), 0.5f * (z.y - zm.y));
        Xs[(row + 1) * NBINS + f] = make_float2(0.5f * (z.y + zm.y), 0.5f * (zm.x - z.x));
    }
}

// ---------------------------------------------------------------------------
// Inverse FFT for mode k, 2 rows packed: Z = g_k*(Xa + i*Xb) (both Hermitian)
// -> complex IFFT -> re = mode row c0, im = row c0+1.
// ---------------------------------------------------------------------------
__global__ __launch_bounds__(512) void fft_inv_packed(const float2* __restrict__ Xs,
                                                      const float* __restrict__ g,
                                                      float* __restrict__ mode,
                                                      int k)
{
    int rp = blockIdx.x;
    int b = rp / 6, c0 = (rp % 6) * 2;
    size_t rowa = (size_t)b * C_IN + c0;
    __shared__ float2 bufA[T_LEN];
    __shared__ float2 bufB[T_LEN];
    const float* gk = g + k * NBINS;
    for (int f = threadIdx.x; f < T_LEN; f += 512) {
        int fe = (f <= 2048) ? f : (T_LEN - f);
        float2 A  = Xs[rowa * NBINS + fe];
        float2 Bv = Xs[(rowa + 1) * NBINS + fe];
        float gv = gk[fe];
        if (f > 2048) { A.y = -A.y; Bv.y = -Bv.y; }   // Hermitian extension
        bufA[f] = make_float2(gv * (A.x - Bv.y), gv * (A.y + Bv.x));
    }
    __syncthreads();
    float2* z = fft_stages(bufA, bufB, 1.f);
    const float invn = 1.f / (float)T_LEN;
    for (int t = threadIdx.x; t < T_LEN; t += 512) {
        mode[rowa * T_LEN + t]       = z[t].x * invn;
        mode[(rowa + 1) * T_LEN + t] = z[t].y * invn;
    }
}

// ---------------------------------------------------------------------------
// Register-tiled conv1d + BN(eval) + ReLU (+ optional mean over T).
// Block = 256 threads = (OUT/8 o-groups) x (TGRPS t-groups); each thread
// computes an 8(o) x 8(t) register tile. Input tile + transposed weights
// staged in LDS, c-chunked to stay under 64 KB.
// ---------------------------------------------------------------------------
template<int CIN, int KW, int OUT, int TILE, int CCHUNK, bool MEAN>
__global__ __launch_bounds__(256) void conv_tiled(
    const float* __restrict__ in,    // (B, CIN, T)
    const float* __restrict__ W,     // (OUT, CIN, KW)
    const float* __restrict__ bias,
    const float* __restrict__ gamma,
    const float* __restrict__ beta,
    float* __restrict__ out,         // (B, OUT, T) or feats (B, 256)
    int k_slot)
{
    constexpr int OGRPS = OUT / 8;
    constexpr int TGRPS = 256 / OGRPS;
    constexpr int PAD = (KW - 1) / 2;
    constexpr int OFF = 4 - PAD;
    constexpr int ROWW = TILE + 16;       // halo 8 both sides
    constexpr int NCHUNK = CIN / CCHUNK;
    static_assert(TGRPS * 8 == TILE, "tile mismatch");
    static_assert(!MEAN || TGRPS == 32, "mean reduce assumes 32-lane groups");

    __shared__ float xs[CCHUNK][ROWW];
    __shared__ float wt[CCHUNK * KW * OUT];   // [c][d][o]

    const int b = blockIdx.y;
    const int tile0 = blockIdx.x * TILE;
    const int tid = threadIdx.x;
    const int ogrp = tid / TGRPS;
    const int tgrp = tid % TGRPS;
    const int t0l = tgrp * 8;
    const int o0 = ogrp * 8;

    float acc[8][8];
#pragma unroll
    for (int i = 0; i < 8; ++i)
#pragma unroll
        for (int j = 0; j < 8; ++j) acc[i][j] = 0.f;

    const bool interior = (tile0 >= 8) && (tile0 + TILE + 8 <= T_LEN);

    for (int ch = 0; ch < NCHUNK; ++ch) {
        if (ch) __syncthreads();
        const float* src = in + ((size_t)b * CIN + ch * CCHUNK) * T_LEN;
        if (interior) {
            for (int i = tid; i < CCHUNK * (ROWW / 4); i += 256) {
                int c = i / (ROWW / 4), j = i % (ROWW / 4);
                ((float4*)&xs[c][0])[j] =
                    ((const float4*)(src + (size_t)c * T_LEN + tile0 - 8))[j];
            }
        } else {
            for (int i = tid; i < CCHUNK * ROWW; i += 256) {
                int c = i / ROWW, j = i % ROWW;
                int t = tile0 - 8 + j;
                xs[c][j] = (t >= 0 && t < T_LEN) ? src[(size_t)c * T_LEN + t] : 0.f;
            }
        }
        constexpr int WTOT = CCHUNK * KW * OUT;
        for (int i = tid; i < WTOT; i += 256) {
            int o = i / (CCHUNK * KW);
            int rem = i % (CCHUNK * KW);
            int c = rem / KW, d = rem % KW;
            wt[(c * KW + d) * OUT + o] = W[((size_t)o * CIN + ch * CCHUNK + c) * KW + d];
        }
        __syncthreads();

        for (int c = 0; c < CCHUNK; ++c) {
            float xr[16];
            const float4* xp = (const float4*)&xs[c][t0l + 4];
            float4 a0 = xp[0], a1 = xp[1], a2 = xp[2], a3 = xp[3];
            xr[0] = a0.x;  xr[1] = a0.y;  xr[2] = a0.z;  xr[3] = a0.w;
            xr[4] = a1.x;  xr[5] = a1.y;  xr[6] = a1.z;  xr[7] = a1.w;
            xr[8] = a2.x;  xr[9] = a2.y;  xr[10] = a2.z; xr[11] = a2.w;
            xr[12] = a3.x; xr[13] = a3.y; xr[14] = a3.z; xr[15] = a3.w;
#pragma unroll
            for (int d = 0; d < KW; ++d) {
                const float4* wp = (const float4*)&wt[(c * KW + d) * OUT + o0];
                float4 w0 = wp[0], w1 = wp[1];
                float wv[8] = {w0.x, w0.y, w0.z, w0.w, w1.x, w1.y, w1.z, w1.w};
#pragma unroll
                for (int os = 0; os < 8; ++os)
#pragma unroll
                    for (int tt = 0; tt < 8; ++tt)
                        acc[os][tt] = fmaf(wv[os], xr[tt + d + OFF], acc[os][tt]);
            }
        }
    }

    const float rs = 1.f / sqrtf(1.f + 1e-5f);
    if (!MEAN) {
#pragma unroll
        for (int os = 0; os < 8; ++os) {
            int o = o0 + os;
            float sc = gamma[o] * rs;
            float bb = fmaf(bias[o], sc, beta[o]);
            float4 v0, v1;
            v0.x = fmaxf(fmaf(acc[os][0], sc, bb), 0.f);
            v0.y = fmaxf(fmaf(acc[os][1], sc, bb), 0.f);
            v0.z = fmaxf(fmaf(acc[os][2], sc, bb), 0.f);
            v0.w = fmaxf(fmaf(acc[os][3], sc, bb), 0.f);
            v1.x = fmaxf(fmaf(acc[os][4], sc, bb), 0.f);
            v1.y = fmaxf(fmaf(acc[os][5], sc, bb), 0.f);
            v1.z = fmaxf(fmaf(acc[os][6], sc, bb), 0.f);
            v1.w = fmaxf(fmaf(acc[os][7], sc, bb), 0.f);
            float* dst = out + ((size_t)b * OUT + o) * T_LEN + tile0 + t0l;
            ((float4*)dst)[0] = v0;
            ((float4*)dst)[1] = v1;
        }
    } else {
#pragma unroll
        for (int os = 0; os < 8; ++os) {
            int o = o0 + os;
            float sc = gamma[o] * rs;
            float bb = fmaf(bias[o], sc, beta[o]);
            float s = 0.f;
#pragma unroll
            for (int tt = 0; tt < 8; ++tt)
                s += fmaxf(fmaf(acc[os][tt], sc, bb), 0.f);
            // reduce across the 32 t-group lanes (contiguous half-wave)
#pragma unroll
            for (int off = 1; off < 32; off <<= 1)
                s += __shfl_xor(s, off, 64);
            if (tgrp == 0)
                atomicAdd(&out[b * (KM * FEAT) + k_slot * FEAT + o], s * (1.f / (float)T_LEN));
        }
    }
}

// ---------------------------------------------------------------------------
// Classifier: feats(B,256) -> relu(@Wc1.T+bc1) -> @Wc2.T+bc2 -> (B,10)
// ---------------------------------------------------------------------------
__global__ __launch_bounds__(128) void classifier_kernel(const float* __restrict__ feats,
                                                         const float* __restrict__ Wc1, // (128,256)
                                                         const float* __restrict__ bc1,
                                                         const float* __restrict__ Wc2, // (10,128)
                                                         const float* __restrict__ bc2,
                                                         float* __restrict__ out)
{
    int b = blockIdx.x;
    int j = threadIdx.x;
    __shared__ float h[128];
    float acc = bc1[j];
    const float* fb = feats + b * 256;
    for (int i = 0; i < 256; ++i) acc = fmaf(fb[i], Wc1[j * 256 + i], acc);
    h[j] = fmaxf(acc, 0.f);
    __syncthreads();
    if (j < 10) {
        float acc2 = bc2[j];
        for (int i = 0; i < 128; ++i) acc2 = fmaf(h[i], Wc2[j * 128 + i], acc2);
        out[b * 10 + j] = acc2;
    }
}

extern "C" void kernel_launch(void* const* d_in, const int* in_sizes, int n_in,
                              void* d_out, int out_size, void* d_ws, size_t ws_size,
                              hipStream_t stream)
{
    const float* x     = (const float*)d_in[0];
    const float* alpha = (const float*)d_in[1];
    const float* tau   = (const float*)d_in[2];
    const float* omega = (const float*)d_in[3];
    const float* W1    = (const float*)d_in[4];
    const float* b1    = (const float*)d_in[5];
    const float* g1    = (const float*)d_in[6];
    const float* be1   = (const float*)d_in[7];
    const float* W2    = (const float*)d_in[8];
    const float* b2    = (const float*)d_in[9];
    const float* g2    = (const float*)d_in[10];
    const float* be2   = (const float*)d_in[11];
    const float* W3    = (const float*)d_in[12];
    const float* b3    = (const float*)d_in[13];
    const float* g3    = (const float*)d_in[14];
    const float* be3   = (const float*)d_in[15];
    const float* Wc1   = (const float*)d_in[16];
    const float* bc1   = (const float*)d_in[17];
    const float* Wc2   = (const float*)d_in[18];
    const float* bc2   = (const float*)d_in[19];

    const int NROWS = B_SZ * C_IN;   // 768
    float* ws = (float*)d_ws;
    float* g     = ws;                                     // 4*2049
    float2* Xs   = (float2*)(ws + 4 * NBINS);              // 768*2049 c
    float* mode  = ws + 4 * NBINS + (size_t)NROWS * NBINS * 2; // 768*4096
    float* h1    = mode + (size_t)NROWS * T_LEN;           // 64*32*4096
    float* h2    = h1 + (size_t)B_SZ * 32 * T_LEN;         // 64*64*4096
    float* feats = h2 + (size_t)B_SZ * 64 * T_LEN;         // 64*256

    gains_kernel<<<(NBINS + 255) / 256, 256, 0, stream>>>(alpha, tau, omega, g);
    zero_kernel<<<64, 256, 0, stream>>>(feats, B_SZ * KM * FEAT);
    fft_fwd_packed<<<NROWS / 2, 512, 0, stream>>>(x, Xs);

    for (int k = 0; k < KM; ++k) {
        fft_inv_packed<<<NROWS / 2, 512, 0, stream>>>(Xs, g, mode, k);
        // conv1: 12 -> 32, kw=7, tile 512
        conv_tiled<12, 7, 32, 512, 12, false><<<dim3(T_LEN / 512, B_SZ), 256, 0, stream>>>(
            mode, W1 + k * 32 * 12 * 7, b1 + k * 32, g1 + k * 32, be1 + k * 32, h1, 0);
        // conv2: 32 -> 64, kw=5, tile 256, c-chunk 16
        conv_tiled<32, 5, 64, 256, 16, false><<<dim3(T_LEN / 256, B_SZ), 256, 0, stream>>>(
            h1, W2 + k * 64 * 32 * 5, b2 + k * 64, g2 + k * 64, be2 + k * 64, h2, 0);
        // conv3 + mean: 64 -> 64, kw=3, tile 256, c-chunk 16
        conv_tiled<64, 3, 64, 256, 16, true><<<dim3(T_LEN / 256, B_SZ), 256, 0, stream>>>(
            h2, W3 + k * 64 * 64 * 3, b3 + k * 64, g3 + k * 64, be3 + k * 64, feats, k);
    }

    classifier_kernel<<<B_SZ, 128, 0, stream>>>(feats, Wc1, bc1, Wc2, bc2, (float*)d_out);
}

// Round 5
// 973.154 us; speedup vs baseline: 3.6830x; 1.2027x over previous
//
#include <hip/hip_runtime.h>
#include <math.h>

#define T_LEN 4096
#define NBINS 2049          // T/2+1
#define B_SZ 64
#define C_IN 12
#define KM 4
#define FEAT 64

// ---------------------------------------------------------------------------
// LDS XOR swizzle (float4-block granularity): spreads stride-32B reads across
// the 8 four-bank groups. bj -> bj ^ ((bj>>3)&7); stays within 8-block group.
// ---------------------------------------------------------------------------
__device__ __forceinline__ int bswz(int bj) { return bj ^ ((bj >> 3) & 7); }
__device__ __forceinline__ int swz(int j)
{
    int bj = j >> 2;
    return ((bj ^ ((bj >> 3) & 7)) << 2) | (j & 3);
}

// ---------------------------------------------------------------------------
// Gains: the Gauss-Seidel UVMD iteration is linear in X with real
// frequency-only coefficients: u_k = g_k(f) * X(f).
// ---------------------------------------------------------------------------
__global__ void gains_kernel(const float* __restrict__ alpha, // (8,4)
                             const float* __restrict__ tau,   // (8)
                             const float* __restrict__ omega, // (4)
                             float* __restrict__ g)           // (4, NBINS)
{
    int f = blockIdx.x * 256 + threadIdx.x;
    if (f >= NBINS) return;
    float freq = 0.5f * (float)f / 2048.0f;
    float a[4] = {0.f, 0.f, 0.f, 0.f};
    float s = 0.f, lamc = 0.f;
    for (int l = 0; l < 8; ++l) {
        for (int k = 0; k < 4; ++k) {
            float r = 1.f - (s - a[k]) + 0.5f * lamc;
            float d = freq - omega[k];
            float denom = 1.f + alpha[l * 4 + k] * d * d;
            float anew = r / denom;
            s += anew - a[k];
            a[k] = anew;
        }
        lamc += tau[l] * (1.f - s);
    }
    for (int k = 0; k < 4; ++k) g[k * NBINS + f] = a[k];
}

// Twiddle LUT: tw[i] = exp(-i*pi*i/2048), i in [0,2048)
__global__ void twiddle_kernel(float2* __restrict__ tw)
{
    int i = blockIdx.x * 256 + threadIdx.x;
    if (i < 2048) {
        float ang = -(float)M_PI * (float)i / 2048.0f;
        float sn, cs;
        sincosf(ang, &sn, &cs);
        tw[i] = make_float2(cs, sn);
    }
}

__global__ void zero_kernel(float* __restrict__ p, int n)
{
    int i = blockIdx.x * 256 + threadIdx.x;
    if (i < n) p[i] = 0.f;
}

// ---------------------------------------------------------------------------
// Stockham radix-2 stages; twiddles from LUT. syf=+1 fwd, -1 inv (conjugate).
// ---------------------------------------------------------------------------
__device__ inline float2* fft_stages(float2* bufA, float2* bufB,
                                     const float2* __restrict__ tw, float syf)
{
    float2* src = bufA;
    float2* dst = bufB;
    for (int s = 0; s < 12; ++s) {
        int m = 1 << s;
        for (int p = threadIdx.x; p < 2048; p += 512) {
            int j = p >> s;
            int jm = j << s;
            float2 c0 = src[p];
            float2 c1 = src[p + 2048];
            float2 w = tw[jm & 2047];        // j << s
            float cs = w.x, sn = syf * w.y;
            float2 d0 = make_float2(c0.x + c1.x, c0.y + c1.y);
            float2 t1 = make_float2(c0.x - c1.x, c0.y - c1.y);
            float2 d1 = make_float2(cs * t1.x - sn * t1.y, cs * t1.y + sn * t1.x);
            dst[jm + p] = d0;
            dst[jm + p + m] = d1;
        }
        __syncthreads();
        float2* tmp = src; src = dst; dst = tmp;
    }
    return src;   // 12 swaps -> back to bufA
}

// ---------------------------------------------------------------------------
// Forward FFT, 2 real rows (channels c0, c0+1) packed into one complex FFT.
// ---------------------------------------------------------------------------
__global__ __launch_bounds__(512) void fft_fwd_packed(const float* __restrict__ x,
                                                      const float2* __restrict__ tw,
                                                      float2* __restrict__ Xs)
{
    int rp = blockIdx.x;            // 0..383
    int b = rp / 6, c0 = (rp % 6) * 2;
    __shared__ float2 bufA[T_LEN];
    __shared__ float2 bufB[T_LEN];
    for (int t = threadIdx.x; t < T_LEN; t += 512) {
        const float* px = x + ((size_t)b * T_LEN + t) * C_IN + c0;
        bufA[t] = make_float2(px[0], px[1]);
    }
    __syncthreads();
    float2* Z = fft_stages(bufA, bufB, tw, 1.f);
    size_t row = (size_t)b * C_IN + c0;
    for (int f = threadIdx.x; f <= 2048; f += 512) {
        float2 z  = Z[f];
        float2 zm = Z[(T_LEN - f) & (T_LEN - 1)];
        // Xa = (Z + conj(Zm))/2 ; Xb = (Z - conj(Zm))/(2i)
        Xs[row * NBINS + f]       = make_float2(0.5f * (z.x + zm.x), 0.5f * (z.y - zm.y));
        Xs[(row + 1) * NBINS + f] = make_float2(0.5f * (z.y + zm.y), 0.5f * (zm.x - z.x));
    }
}

// ---------------------------------------------------------------------------
// Inverse FFT for mode k, 2 rows packed: Z = g_k*(Xa + i*Xb) (both Hermitian)
// -> complex IFFT -> re = mode row c0, im = row c0+1.
// ---------------------------------------------------------------------------
__global__ __launch_bounds__(512) void fft_inv_packed(const float2* __restrict__ Xs,
                                                      const float* __restrict__ g,
                                                      const float2* __restrict__ tw,
                                                      float* __restrict__ mode,
                                                      int k)
{
    int rp = blockIdx.x;
    int b = rp / 6, c0 = (rp % 6) * 2;
    size_t rowa = (size_t)b * C_IN + c0;
    __shared__ float2 bufA[T_LEN];
    __shared__ float2 bufB[T_LEN];
    const float* gk = g + k * NBINS;
    for (int f = threadIdx.x; f < T_LEN; f += 512) {
        int fe = (f <= 2048) ? f : (T_LEN - f);
        float2 A  = Xs[rowa * NBINS + fe];
        float2 Bv = Xs[(rowa + 1) * NBINS + fe];
        float gv = gk[fe];
        if (f > 2048) { A.y = -A.y; Bv.y = -Bv.y; }   // Hermitian extension
        bufA[f] = make_float2(gv * (A.x - Bv.y), gv * (A.y + Bv.x));
    }
    __syncthreads();
    float2* z = fft_stages(bufA, bufB, tw, -1.f);
    const float invn = 1.f / (float)T_LEN;
    for (int t = threadIdx.x; t < T_LEN; t += 512) {
        mode[rowa * T_LEN + t]       = z[t].x * invn;
        mode[(rowa + 1) * T_LEN + t] = z[t].y * invn;
    }
}

// ---------------------------------------------------------------------------
// Register-tiled conv1d + BN(eval) + ReLU (+ optional mean over T).
// Block = 256 threads = (OUT/8 o-groups) x (TGRPS t-groups); each thread
// computes an 8(o) x 8(t) register tile. Input tile (XOR-swizzled) +
// transposed weights staged in LDS, c-chunked to stay under 64 KB.
// ---------------------------------------------------------------------------
template<int CIN, int KW, int OUT, int TILE, int CCHUNK, bool MEAN>
__global__ __launch_bounds__(256) void conv_tiled(
    const float* __restrict__ in,    // (B, CIN, T)
    const float* __restrict__ W,     // (OUT, CIN, KW)
    const float* __restrict__ bias,
    const float* __restrict__ gamma,
    const float* __restrict__ beta,
    float* __restrict__ out,         // (B, OUT, T) or feats (B, 256)
    int k_slot)
{
    constexpr int OGRPS = OUT / 8;
    constexpr int TGRPS = 256 / OGRPS;
    constexpr int PAD = (KW - 1) / 2;
    constexpr int OFF = 4 - PAD;
    constexpr int ROWW = TILE + 16;       // halo 8 both sides
    constexpr int NCHUNK = CIN / CCHUNK;
    static_assert(TGRPS * 8 == TILE, "tile mismatch");
    static_assert(!MEAN || TGRPS == 32, "mean reduce assumes 32-lane groups");

    __shared__ float xs[CCHUNK][ROWW];
    __shared__ float wt[CCHUNK * KW * OUT];   // [c][d][o]

    const int b = blockIdx.y;
    const int tile0 = blockIdx.x * TILE;
    const int tid = threadIdx.x;
    const int ogrp = tid / TGRPS;
    const int tgrp = tid % TGRPS;
    const int t0l = tgrp * 8;
    const int o0 = ogrp * 8;

    float acc[8][8];
#pragma unroll
    for (int i = 0; i < 8; ++i)
#pragma unroll
        for (int j = 0; j < 8; ++j) acc[i][j] = 0.f;

    const bool interior = (tile0 >= 8) && (tile0 + TILE + 8 <= T_LEN);

    for (int ch = 0; ch < NCHUNK; ++ch) {
        if (ch) __syncthreads();
        const float* src = in + ((size_t)b * CIN + ch * CCHUNK) * T_LEN;
        if (interior) {
            for (int i = tid; i < CCHUNK * (ROWW / 4); i += 256) {
                int c = i / (ROWW / 4), j = i % (ROWW / 4);
                ((float4*)&xs[c][0])[bswz(j)] =
                    ((const float4*)(src + (size_t)c * T_LEN + tile0 - 8))[j];
            }
        } else {
            for (int i = tid; i < CCHUNK * ROWW; i += 256) {
                int c = i / ROWW, j = i % ROWW;
                int t = tile0 - 8 + j;
                xs[c][swz(j)] = (t >= 0 && t < T_LEN) ? src[(size_t)c * T_LEN + t] : 0.f;
            }
        }
        constexpr int WTOT = CCHUNK * KW * OUT;
        for (int i = tid; i < WTOT; i += 256) {
            int o = i / (CCHUNK * KW);
            int rem = i % (CCHUNK * KW);
            int c = rem / KW, d = rem % KW;
            wt[(c * KW + d) * OUT + o] = W[((size_t)o * CIN + ch * CCHUNK + c) * KW + d];
        }
        __syncthreads();

        for (int c = 0; c < CCHUNK; ++c) {
            float xr[16];
            const float4* xp4 = (const float4*)&xs[c][0];
            const int bb = (t0l >> 2) + 1;            // (t0l + 4) / 4
            float4 a0 = xp4[bswz(bb)];
            float4 a1 = xp4[bswz(bb + 1)];
            float4 a2 = xp4[bswz(bb + 2)];
            float4 a3 = xp4[bswz(bb + 3)];
            xr[0] = a0.x;  xr[1] = a0.y;  xr[2] = a0.z;  xr[3] = a0.w;
            xr[4] = a1.x;  xr[5] = a1.y;  xr[6] = a1.z;  xr[7] = a1.w;
            xr[8] = a2.x;  xr[9] = a2.y;  xr[10] = a2.z; xr[11] = a2.w;
            xr[12] = a3.x; xr[13] = a3.y; xr[14] = a3.z; xr[15] = a3.w;
#pragma unroll
            for (int d = 0; d < KW; ++d) {
                const float4* wp = (const float4*)&wt[(c * KW + d) * OUT + o0];
                float4 w0 = wp[0], w1 = wp[1];
                float wv[8] = {w0.x, w0.y, w0.z, w0.w, w1.x, w1.y, w1.z, w1.w};
#pragma unroll
                for (int os = 0; os < 8; ++os)
#pragma unroll
                    for (int tt = 0; tt < 8; ++tt)
                        acc[os][tt] = fmaf(wv[os], xr[tt + d + OFF], acc[os][tt]);
            }
        }
    }

    const float rs = 1.f / sqrtf(1.f + 1e-5f);
    if (!MEAN) {
#pragma unroll
        for (int os = 0; os < 8; ++os) {
            int o = o0 + os;
            float sc = gamma[o] * rs;
            float bb = fmaf(bias[o], sc, beta[o]);
            float4 v0, v1;
            v0.x = fmaxf(fmaf(acc[os][0], sc, bb), 0.f);
            v0.y = fmaxf(fmaf(acc[os][1], sc, bb), 0.f);
            v0.z = fmaxf(fmaf(acc[os][2], sc, bb), 0.f);
            v0.w = fmaxf(fmaf(acc[os][3], sc, bb), 0.f);
            v1.x = fmaxf(fmaf(acc[os][4], sc, bb), 0.f);
            v1.y = fmaxf(fmaf(acc[os][5], sc, bb), 0.f);
            v1.z = fmaxf(fmaf(acc[os][6], sc, bb), 0.f);
            v1.w = fmaxf(fmaf(acc[os][7], sc, bb), 0.f);
            float* dst = out + ((size_t)b * OUT + o) * T_LEN + tile0 + t0l;
            ((float4*)dst)[0] = v0;
            ((float4*)dst)[1] = v1;
        }
    } else {
#pragma unroll
        for (int os = 0; os < 8; ++os) {
            int o = o0 + os;
            float sc = gamma[o] * rs;
            float bb = fmaf(bias[o], sc, beta[o]);
            float s = 0.f;
#pragma unroll
            for (int tt = 0; tt < 8; ++tt)
                s += fmaxf(fmaf(acc[os][tt], sc, bb), 0.f);
            // reduce across the 32 t-group lanes (contiguous half-wave)
#pragma unroll
            for (int off = 1; off < 32; off <<= 1)
                s += __shfl_xor(s, off, 64);
            if (tgrp == 0)
                atomicAdd(&out[b * (KM * FEAT) + k_slot * FEAT + o], s * (1.f / (float)T_LEN));
        }
    }
}

// ---------------------------------------------------------------------------
// Classifier: feats(B,256) -> relu(@Wc1.T+bc1) -> @Wc2.T+bc2 -> (B,10)
// ---------------------------------------------------------------------------
__global__ __launch_bounds__(128) void classifier_kernel(const float* __restrict__ feats,
                                                         const float* __restrict__ Wc1, // (128,256)
                                                         const float* __restrict__ bc1,
                                                         const float* __restrict__ Wc2, // (10,128)
                                                         const float* __restrict__ bc2,
                                                         float* __restrict__ out)
{
    int b = blockIdx.x;
    int j = threadIdx.x;
    __shared__ float h[128];
    float acc = bc1[j];
    const float* fb = feats + b * 256;
    for (int i = 0; i < 256; ++i) acc = fmaf(fb[i], Wc1[j * 256 + i], acc);
    h[j] = fmaxf(acc, 0.f);
    __syncthreads();
    if (j < 10) {
        float acc2 = bc2[j];
        for (int i = 0; i < 128; ++i) acc2 = fmaf(h[i], Wc2[j * 128 + i], acc2);
        out[b * 10 + j] = acc2;
    }
}

extern "C" void kernel_launch(void* const* d_in, const int* in_sizes, int n_in,
                              void* d_out, int out_size, void* d_ws, size_t ws_size,
                              hipStream_t stream)
{
    const float* x     = (const float*)d_in[0];
    const float* alpha = (const float*)d_in[1];
    const float* tau   = (const float*)d_in[2];
    const float* omega = (const float*)d_in[3];
    const float* W1    = (const float*)d_in[4];
    const float* b1    = (const float*)d_in[5];
    const float* g1    = (const float*)d_in[6];
    const float* be1   = (const float*)d_in[7];
    const float* W2    = (const float*)d_in[8];
    const float* b2    = (const float*)d_in[9];
    const float* g2    = (const float*)d_in[10];
    const float* be2   = (const float*)d_in[11];
    const float* W3    = (const float*)d_in[12];
    const float* b3    = (const float*)d_in[13];
    const float* g3    = (const float*)d_in[14];
    const float* be3   = (const float*)d_in[15];
    const float* Wc1   = (const float*)d_in[16];
    const float* bc1   = (const float*)d_in[17];
    const float* Wc2   = (const float*)d_in[18];
    const float* bc2   = (const float*)d_in[19];

    const int NROWS = B_SZ * C_IN;   // 768
    float* ws = (float*)d_ws;
    float2* tw   = (float2*)ws;                            // 2048 float2
    float* g     = ws + 4096;                              // 4*2049
    float2* Xs   = (float2*)(ws + 4096 + 4 * NBINS);       // 768*2049 c
    float* mode  = ws + 4096 + 4 * NBINS + (size_t)NROWS * NBINS * 2;
    float* h1    = mode + (size_t)NROWS * T_LEN;           // 64*32*4096
    float* h2    = h1 + (size_t)B_SZ * 32 * T_LEN;         // 64*64*4096
    float* feats = h2 + (size_t)B_SZ * 64 * T_LEN;         // 64*256

    gains_kernel<<<(NBINS + 255) / 256, 256, 0, stream>>>(alpha, tau, omega, g);
    twiddle_kernel<<<8, 256, 0, stream>>>(tw);
    zero_kernel<<<64, 256, 0, stream>>>(feats, B_SZ * KM * FEAT);
    fft_fwd_packed<<<NROWS / 2, 512, 0, stream>>>(x, tw, Xs);

    for (int k = 0; k < KM; ++k) {
        fft_inv_packed<<<NROWS / 2, 512, 0, stream>>>(Xs, g, tw, mode, k);
        // conv1: 12 -> 32, kw=7, tile 512
        conv_tiled<12, 7, 32, 512, 12, false><<<dim3(T_LEN / 512, B_SZ), 256, 0, stream>>>(
            mode, W1 + k * 32 * 12 * 7, b1 + k * 32, g1 + k * 32, be1 + k * 32, h1, 0);
        // conv2: 32 -> 64, kw=5, tile 256, c-chunk 16
        conv_tiled<32, 5, 64, 256, 16, false><<<dim3(T_LEN / 256, B_SZ), 256, 0, stream>>>(
            h1, W2 + k * 64 * 32 * 5, b2 + k * 64, g2 + k * 64, be2 + k * 64, h2, 0);
        // conv3 + mean: 64 -> 64, kw=3, tile 256, c-chunk 16
        conv_tiled<64, 3, 64, 256, 16, true><<<dim3(T_LEN / 256, B_SZ), 256, 0, stream>>>(
            h2, W3 + k * 64 * 64 * 3, b3 + k * 64, g3 + k * 64, be3 + k * 64, feats, k);
    }

    classifier_kernel<<<B_SZ, 128, 0, stream>>>(feats, Wc1, bc1, Wc2, bc2, (float*)d_out);
}